// Round 11
// baseline (477.022 us; speedup 1.0000x reference)
//
#include <hip/hip_runtime.h>
#include <hip/hip_bf16.h>
#include <float.h>

#define NN 4000      // nodes
#define NE 20000     // edges
#define DD 512       // D
#define NT 4         // towers
#define FO 128       // F_OUT
#define NG 32
#define NC 10
#define XGW 4096     // XG row width: 2048 xi + 2048 xj (gx goes to OF)
#define AVGLOG 1.2548916493836102f
#define EPS_STD_ 1e-5f
#define EPS_BN_ 1e-5f

typedef __bf16 bf16x8 __attribute__((ext_vector_type(8)));
typedef float  f32x4  __attribute__((ext_vector_type(4)));

__device__ __forceinline__ void async_copy16(const void* g, void* l) {
    __builtin_amdgcn_global_load_lds((const __attribute__((address_space(1))) void*)g,
                                     (__attribute__((address_space(3))) void*)l, 16, 0, 0);
}

// =============== k_xg: XG[n][0:4096] = XB @ [Wi|Wj]^T (bf16); OF = XB @ W0^T + post_b (fp32) ===============
// 128x128 tile, K=512, BK=32 (proven core). grid (36, 32): x<32 -> XG, x>=32 -> OF.
__global__ __launch_bounds__(256) void k_xg(const __bf16* __restrict__ XB, const __bf16* __restrict__ WCAT,
                                            const float* __restrict__ pb,
                                            __bf16* __restrict__ XG, float* __restrict__ OF,
                                            float* __restrict__ BN, float* __restrict__ PL, int zero_pl) {
    const int m0 = blockIdx.y * 128, n0 = blockIdx.x * 128;
    __shared__ __bf16 As[128 * 32];
    __shared__ __bf16 Bs[128 * 32];
    const int tid = threadIdx.x;
    const int wave = tid >> 6, lane = tid & 63;
    const int wm = (wave >> 1) * 64, wn = (wave & 1) * 64;
    const int fr = lane & 15, fq = lane >> 4;
    const int fk = fq * 8;
    const int srow = lane >> 2, skc = (lane & 3) * 8;

    f32x4 acc[4][4];
    const f32x4 zero = {0.f, 0.f, 0.f, 0.f};
#pragma unroll
    for (int i = 0; i < 4; ++i)
#pragma unroll
        for (int j = 0; j < 4; ++j) acc[i][j] = zero;

    for (int k0 = 0; k0 < 512; k0 += 32) {
#pragma unroll
        for (int q = 0; q < 2; ++q) {
            const int row = wave * 32 + q * 16 + srow;
            int ar = m0 + row; if (ar > NN - 1) ar = NN - 1;
            async_copy16(XB + (size_t)ar * 512 + k0 + skc, As + wave * 1024 + q * 512);
            async_copy16(WCAT + (size_t)(n0 + row) * 512 + k0 + skc, Bs + wave * 1024 + q * 512);
        }
        __syncthreads();
        bf16x8 af[4], bfr[4];
#pragma unroll
        for (int mi = 0; mi < 4; ++mi) af[mi]  = *(const bf16x8*)(As + (wm + mi * 16 + fr) * 32 + fk);
#pragma unroll
        for (int ni = 0; ni < 4; ++ni) bfr[ni] = *(const bf16x8*)(Bs + (wn + ni * 16 + fr) * 32 + fk);
#pragma unroll
        for (int mi = 0; mi < 4; ++mi)
#pragma unroll
            for (int ni = 0; ni < 4; ++ni)
                acc[mi][ni] = __builtin_amdgcn_mfma_f32_16x16x32_bf16(af[mi], bfr[ni], acc[mi][ni], 0, 0, 0);
        __syncthreads();
    }
    if (n0 < 4096) {
#pragma unroll
        for (int mi = 0; mi < 4; ++mi) {
#pragma unroll
            for (int ni = 0; ni < 4; ++ni) {
                const int col = n0 + wn + ni * 16 + fr;
                const int rb = m0 + wm + mi * 16 + fq * 4;
#pragma unroll
                for (int r = 0; r < 4; ++r) {
                    const int rowc = rb + r;
                    if (rowc < NN) XG[(size_t)rowc * XGW + col] = (__bf16)acc[mi][ni][r];
                }
            }
        }
    } else {
        const int ocb = n0 - 4096;
#pragma unroll
        for (int mi = 0; mi < 4; ++mi) {
#pragma unroll
            for (int ni = 0; ni < 4; ++ni) {
                const int oc = ocb + wn + ni * 16 + fr;
                const float bv = pb[oc];
                const int rb = m0 + wm + mi * 16 + fq * 4;
#pragma unroll
                for (int r = 0; r < 4; ++r) {
                    const int rowc = rb + r;
                    if (rowc < NN) OF[(size_t)rowc * 512 + oc] = acc[mi][ni][r] + bv;
                }
            }
        }
    }
    if (blockIdx.x == 32 && blockIdx.y == 0) {
        BN[tid] = 0.f; BN[256 + tid] = 0.f; BN[512 + tid] = 0.f; BN[768 + tid] = 0.f;
        if (zero_pl)
            for (int i = tid; i < NG * DD; i += 256) PL[i] = 0.f;
    }
}

// =============== k_gw: tower GEMM 128x128, split-K=2, BK=32, XCD-swizzled ===============
// 1D grid 768. Decode so the 3 same-A blocks (xg=0..2) share bid%8 -> same XCD (L2 A-sharing).
__global__ __launch_bounds__(256) void k_gw(const __bf16* __restrict__ AB, const __bf16* __restrict__ WTT,
                                            const float* __restrict__ amp, const float* __restrict__ ramp,
                                            __bf16* __restrict__ GWPb) {
    const int bid = blockIdx.x;
    const int xcd = bid & 7;
    const int q = bid >> 3;        // 0..95
    const int xg = q % 3;          // weight group: 0:P1 w=1, 1:P2 w=amp, 2:P3 w=ramp
    const int ghi = q / 3;         // 0..31
    const int g = ghi * 8 + xcd;   // 0..255 = y + 32*z
    const int y = g & 31, z = g >> 5;
    const int t = z & 3, kh = z >> 2;
    const int m0 = y * 128;
    const __bf16* A  = AB  + (size_t)t * 2048 + (size_t)kh * 1024;
    const __bf16* BT = WTT + (size_t)t * 384 * 2048 + (size_t)xg * 128 * 2048 + (size_t)kh * 1024;
    __shared__ __bf16 As[128 * 32];
    __shared__ __bf16 Bs[128 * 32];
    const int tid = threadIdx.x;
    const int wave = tid >> 6, lane = tid & 63;
    const int wm = (wave >> 1) * 64, wn = (wave & 1) * 64;
    const int fr = lane & 15, fq = lane >> 4;
    const int fk = fq * 8;
    const int srow = lane >> 2, skc = (lane & 3) * 8;

    f32x4 acc[4][4];
    const f32x4 zero = {0.f, 0.f, 0.f, 0.f};
#pragma unroll
    for (int i = 0; i < 4; ++i)
#pragma unroll
        for (int j = 0; j < 4; ++j) acc[i][j] = zero;

    for (int k0 = 0; k0 < 1024; k0 += 32) {
#pragma unroll
        for (int p = 0; p < 2; ++p) {
            const int row = wave * 32 + p * 16 + srow;
            int ar = m0 + row; if (ar > NN - 1) ar = NN - 1;
            async_copy16(A + (size_t)ar * 8192 + k0 + skc, As + wave * 1024 + p * 512);
            async_copy16(BT + (size_t)row * 2048 + k0 + skc, Bs + wave * 1024 + p * 512);
        }
        __syncthreads();
        bf16x8 af[4], bfr[4];
#pragma unroll
        for (int mi = 0; mi < 4; ++mi) af[mi]  = *(const bf16x8*)(As + (wm + mi * 16 + fr) * 32 + fk);
#pragma unroll
        for (int ni = 0; ni < 4; ++ni) bfr[ni] = *(const bf16x8*)(Bs + (wn + ni * 16 + fr) * 32 + fk);
#pragma unroll
        for (int mi = 0; mi < 4; ++mi)
#pragma unroll
            for (int ni = 0; ni < 4; ++ni)
                acc[mi][ni] = __builtin_amdgcn_mfma_f32_16x16x32_bf16(af[mi], bfr[ni], acc[mi][ni], 0, 0, 0);
        __syncthreads();
    }
    const int p = xg * 2 + kh;
    __bf16* P = GWPb + (size_t)p * NN * 512 + (size_t)t * 128;
#pragma unroll
    for (int mi = 0; mi < 4; ++mi) {
        const int rb = m0 + wm + mi * 16 + fq * 4;
#pragma unroll
        for (int r = 0; r < 4; ++r) {
            const int row = rb + r;
            if (row < NN) {
                const float w = (xg == 0) ? 1.0f : (xg == 1 ? amp[row] : ramp[row]);
#pragma unroll
                for (int ni = 0; ni < 4; ++ni)
                    P[(size_t)row * 512 + wn + ni * 16 + fr] = (__bf16)(acc[mi][ni][r] * w);
            }
        }
    }
}

// OB[n][c] = OF[n][c] + sum of 6 bf16 partial planes -> bf16. grid 1000 x 256, 8 elems/thread.
__global__ void k_combine(const float* __restrict__ OF, const __bf16* __restrict__ GWPb,
                          __bf16* __restrict__ OB) {
    const size_t idx8 = ((size_t)blockIdx.x * 256 + threadIdx.x) * 8;
    float4 o0 = *(const float4*)(OF + idx8);
    float4 o1 = *(const float4*)(OF + idx8 + 4);
    float s[8] = {o0.x, o0.y, o0.z, o0.w, o1.x, o1.y, o1.z, o1.w};
#pragma unroll
    for (int p = 0; p < 6; ++p) {
        bf16x8 g = *(const bf16x8*)(GWPb + (size_t)p * NN * 512 + idx8);
#pragma unroll
        for (int i = 0; i < 8; ++i) s[i] += (float)g[i];
    }
    bf16x8 ov;
#pragma unroll
    for (int i = 0; i < 8; ++i) ov[i] = (__bf16)s[i];
    *(bf16x8*)(OB + idx8) = ov;
}

// =============== k_lin: H = OB @ lin_w^T + lin_b (64x128 tile) + fused BN stats ===============
__global__ __launch_bounds__(256) void k_lin(const __bf16* __restrict__ OB, const __bf16* __restrict__ WLINT,
                                             const float* __restrict__ bl, float* __restrict__ H,
                                             float* __restrict__ BN) {
    const int n0c = blockIdx.x * 128, m0 = blockIdx.y * 64;
    __shared__ __bf16 As[64 * 32];
    __shared__ __bf16 Bs[128 * 32];
    __shared__ float bnS[128], bnQ[128];
    const int tid = threadIdx.x;
    if (tid < 128) { bnS[tid] = 0.f; bnQ[tid] = 0.f; }
    const int wave = tid >> 6, lane = tid & 63;
    const int wr = wave >> 1, wc = wave & 1;
    const int fr = lane & 15, fq = lane >> 4;
    f32x4 acc[2][4];
    const f32x4 zero = {0.f, 0.f, 0.f, 0.f};
#pragma unroll
    for (int i = 0; i < 2; ++i)
#pragma unroll
        for (int j = 0; j < 4; ++j) acc[i][j] = zero;

    const int ar = tid >> 2, akc = (tid & 3) * 8;
    int arow = m0 + ar; if (arow > NN - 1) arow = NN - 1;
    for (int k0 = 0; k0 < 512; k0 += 32) {
        async_copy16(OB + (size_t)arow * 512 + k0 + akc, As + tid * 8);
#pragma unroll
        for (int i = 0; i < 2; ++i) {
            const int cb = tid + 256 * i;
            const int br = cb >> 2, bkc = (cb & 3) * 8;
            async_copy16(WLINT + (size_t)(n0c + br) * 512 + k0 + bkc, Bs + cb * 8);
        }
        __syncthreads();
        bf16x8 a[2], b[4];
#pragma unroll
        for (int mi = 0; mi < 2; ++mi) a[mi] = *(const bf16x8*)(As + (wr * 32 + mi * 16 + fr) * 32 + fq * 8);
#pragma unroll
        for (int ni = 0; ni < 4; ++ni) b[ni] = *(const bf16x8*)(Bs + (wc * 64 + ni * 16 + fr) * 32 + fq * 8);
#pragma unroll
        for (int mi = 0; mi < 2; ++mi)
#pragma unroll
            for (int ni = 0; ni < 4; ++ni)
                acc[mi][ni] = __builtin_amdgcn_mfma_f32_16x16x32_bf16(a[mi], b[ni], acc[mi][ni], 0, 0, 0);
        __syncthreads();
    }
#pragma unroll
    for (int ni = 0; ni < 4; ++ni) {
        const int lc = wc * 64 + ni * 16 + fr;
        const int col = n0c + lc;
        const float bv = bl[col];
        float s = 0.f, q = 0.f;
#pragma unroll
        for (int mi = 0; mi < 2; ++mi) {
#pragma unroll
            for (int r = 0; r < 4; ++r) {
                const int rowc = m0 + wr * 32 + mi * 16 + fq * 4 + r;
                if (rowc < NN) {
                    const float v = acc[mi][ni][r] + bv;
                    H[(size_t)rowc * 512 + col] = v;
                    s += v; q += v * v;
                }
            }
        }
        atomicAdd(&bnS[lc], s); atomicAdd(&bnQ[lc], q);
    }
    __syncthreads();
    if (tid < 128) {
        atomicAdd(&BN[n0c + tid], bnS[tid]);
        atomicAdd(&BN[512 + n0c + tid], bnQ[tid]);
    }
}

// =============== fused weight transpose/convert + edge-message table, BOTH layers in one launch ===============
__device__ __forceinline__ void tr32(const float* __restrict__ S, int sld,
                                     __bf16* __restrict__ D, int dld, int tx, int ty) {
    __shared__ float t[32][33];
    const int y0 = ty * 4;
#pragma unroll
    for (int i = 0; i < 4; ++i) t[y0 + i][tx] = S[(size_t)(y0 + i) * sld + tx];
    __syncthreads();
#pragma unroll
    for (int i = 0; i < 4; ++i) D[(size_t)(y0 + i) * dld + tx] = (__bf16)t[tx][y0 + i];
}

// per layer jobs: [0,2048) pre Wi/Wj; [2048,2304) W0; [2304,5376) WTT; [5376,5632) WLINT; [5632,5696) EM
__global__ __launch_bounds__(256) void k_tr(const float* __restrict__ pre_w, const float* __restrict__ post_w,
                                            const float* __restrict__ lin_w,
                                            const float* __restrict__ eemb, const float* __restrict__ eew_b,
                                            const float* __restrict__ eeb_b, const float* __restrict__ pre_b,
                                            __bf16* __restrict__ WCAT, __bf16* __restrict__ WTT,
                                            __bf16* __restrict__ WLINT, float* __restrict__ EM) {
    int id = blockIdx.x;
    const int lay = (id >= 5696) ? 1 : 0;
    id -= lay * 5696;
    const float* pw   = pre_w  + (size_t)lay * NT * 3 * 512 * 512;
    const float* pow_ = post_w + (size_t)lay * NT * 6656 * 128;
    const float* lw   = lin_w  + (size_t)lay * 512 * 512;
    const float* eew  = eew_b  + (size_t)lay * 50 * 512;
    const float* eeb  = eeb_b  + (size_t)lay * 512;
    const float* pb   = pre_b  + (size_t)lay * NT * 512;
    __bf16* WCATl  = WCAT  + (size_t)lay * 4608 * 512;
    __bf16* WTTl   = WTT   + (size_t)lay * NT * 384 * 2048;
    __bf16* WLINTl = WLINT + (size_t)lay * 512 * 512;
    float*  EMl    = EM    + (size_t)lay * 4096;
    const int tx = threadIdx.x & 31, ty = threadIdx.x >> 5;
    if (id < 2048) {
        const int z = id >> 8, r = id & 255;
        const int t = z & 3, half = z >> 2;
        const int x = r & 15, y = r >> 4;
        const float* S = pw + ((size_t)(t * 1536 + half * 512 + y * 32)) * 512 + x * 32;
        __bf16* D = WCATl + ((size_t)(half * 2048 + t * 512 + x * 32)) * 512 + y * 32;
        tr32(S, 512, D, 512, tx, ty);
    } else if (id < 2304) {
        const int id3 = id - 2048;
        const int t = id3 >> 6, r = id3 & 63;
        const int x = r & 3, y = r >> 2;
        const float* S = pow_ + ((size_t)(t * 6656 + y * 32)) * 128 + x * 32;
        __bf16* D = WCATl + ((size_t)(4096 + t * 128 + x * 32)) * 512 + y * 32;
        tr32(S, 128, D, 512, tx, ty);
    } else if (id < 5376) {
        const int id4 = id - 2304;
        const int z = id4 >> 8, r = id4 & 255;
        const int t = z / 3, w = z % 3;
        const int x = r & 3, y = r >> 2;
        const float* S = pow_ + ((size_t)(t * 6656 + 512 + w * 2048 + y * 32)) * 128 + x * 32;
        __bf16* D = WTTl + (size_t)t * 384 * 2048 + ((size_t)(w * 128 + x * 32)) * 2048 + y * 32;
        tr32(S, 128, D, 2048, tx, ty);
    } else if (id < 5632) {
        const int r = id - 5376;
        const int x = r & 15, y = r >> 4;
        const float* S = lw + (size_t)y * 32 * 512 + x * 32;
        __bf16* D = WLINTl + (size_t)x * 32 * 512 + y * 32;
        tr32(S, 512, D, 512, tx, ty);
    } else {
        __shared__ float eks[512];
        __shared__ float part[4][64];
        const int tid = threadIdx.x;
        const int id5 = id - 5632;
        const int k = id5 >> 5;
        const int g0 = (id5 & 31) * 64;
#pragma unroll
        for (int h = 0; h < 2; ++h) {
            const int f = tid + h * 256;
            float s = eeb[f];
            for (int c = 0; c < 50; ++c) s += eemb[k * 50 + c] * eew[(size_t)c * 512 + f];
            eks[f] = s;
        }
        __syncthreads();
        const int wave = tid >> 6, lane = tid & 63;
        const int g = g0 + lane;
        const int t = g >> 9, d = g & 511;
        const float* Wp = pw + ((size_t)(t * 1536 + 1024)) * 512 + d;
        float s = 0.f;
        const int f0 = wave * 128;
#pragma unroll 4
        for (int f = f0; f < f0 + 128; ++f) s += eks[f] * Wp[(size_t)f * 512];
        part[wave][lane] = s;
        __syncthreads();
        if (tid < 64) {
            const int gg = g0 + tid;
            EMl[k * 2048 + gg] = pb[gg] + part[0][tid] + part[1][tid] + part[2][tid] + part[3][tid];
        }
    }
}

// ---------------- graph prep ----------------
__global__ void k_count(const int* __restrict__ dst, int* __restrict__ cnt) {
    int e = blockIdx.x * 256 + threadIdx.x;
    if (e < NE) atomicAdd(&cnt[dst[e]], 1);
}

__global__ __launch_bounds__(1024) void k_scan_bx(const int* __restrict__ cnt, int* __restrict__ offs,
                                                  float* __restrict__ amp, float* __restrict__ ramp,
                                                  const float* __restrict__ nemb, const float* __restrict__ acts,
                                                  const float* __restrict__ pew, const float* __restrict__ peb,
                                                  const int* __restrict__ gidx, __bf16* __restrict__ XB) {
    const int t = threadIdx.x;
    if (blockIdx.x == 0) {
        __shared__ int part[1024];
        const int base = t * 4;
        int loc[4]; int s = 0;
#pragma unroll
        for (int i = 0; i < 4; ++i) { int v = (base + i < NN) ? cnt[base + i] : 0; loc[i] = s; s += v; }
        part[t] = s;
        __syncthreads();
        for (int o = 1; o < 1024; o <<= 1) {
            int v = (t >= o) ? part[t - o] : 0;
            __syncthreads();
            part[t] += v;
            __syncthreads();
        }
        const int pre = (t > 0) ? part[t - 1] : 0;
#pragma unroll
        for (int i = 0; i < 4; ++i) if (base + i < NN) offs[base + i] = pre + loc[i];
        if (t == 1023) offs[NN] = part[1023];
        for (int n = t; n < NN; n += 1024) {
            float deg = fmaxf((float)cnt[n], 1.0f);
            float a = logf(deg + 1.0f) / AVGLOG;
            amp[n] = a; ramp[n] = 1.0f / a;
        }
    } else {
        const int idx = (blockIdx.x - 1) * 1024 + t;
        const int n = idx >> 9, d = idx & 511;
        float v = nemb[(size_t)gidx[n] * DD + d] + acts[n * 2] * pew[d] + acts[n * 2 + 1] * pew[DD + d] + peb[d];
        XB[idx] = (__bf16)v;
    }
}

// epack = (src << 1) | sign
__global__ void k_fill(const int* __restrict__ src, const int* __restrict__ dst,
                       const int* __restrict__ sgn, const int* __restrict__ offs,
                       int* __restrict__ fill, int* __restrict__ epack) {
    int e = blockIdx.x * 256 + threadIdx.x;
    if (e < NE) {
        int d = dst[e];
        int pos = offs[d] + atomicAdd(&fill[d], 1);
        epack[pos] = (src[e] << 1) | sgn[e];
    }
}

// ---------------- aggregation: one block per dst node, LDS index stage + 2-way unrolled ----------------
__global__ __launch_bounds__(256) void k_agg(const __bf16* __restrict__ XG, const float* __restrict__ EM,
                                             const int* __restrict__ offs, const int* __restrict__ cnt,
                                             const int* __restrict__ epack, __bf16* __restrict__ AB) {
    const int n = blockIdx.x;
    const int g = threadIdx.x * 8;
    __shared__ int se[64];
    const int j0 = offs[n];
    const int deg = offs[n + 1] - j0;
    const int degc = deg < 64 ? deg : 64;
    if (threadIdx.x < degc) se[threadIdx.x] = epack[j0 + threadIdx.x];
    __syncthreads();
    float xid[8], em0[8], em1[8];
    {
        bf16x8 xb = *(const bf16x8*)(XG + (size_t)n * XGW + g);
#pragma unroll
        for (int i = 0; i < 8; ++i) xid[i] = (float)xb[i];
    }
    *(float4*)&em0[0] = *(const float4*)&EM[g];
    *(float4*)&em0[4] = *(const float4*)&EM[g + 4];
    *(float4*)&em1[0] = *(const float4*)&EM[2048 + g];
    *(float4*)&em1[4] = *(const float4*)&EM[2048 + g + 4];
    float s1[8], s2[8], mn[8], mx[8];
#pragma unroll
    for (int i = 0; i < 8; ++i) { s1[i] = 0.f; s2[i] = 0.f; mn[i] = FLT_MAX; mx[i] = -FLT_MAX; }

    int jj = 0;
    for (; jj + 2 <= degc; jj += 2) {
        const int e0 = se[jj], e1 = se[jj + 1];
        bf16x8 x0 = *(const bf16x8*)(XG + (size_t)(e0 >> 1) * XGW + 2048 + g);
        bf16x8 x1 = *(const bf16x8*)(XG + (size_t)(e1 >> 1) * XGW + 2048 + g);
        const int sg0 = e0 & 1, sg1 = e1 & 1;
#pragma unroll
        for (int i = 0; i < 8; ++i) {
            float m = xid[i] + (float)x0[i] + (sg0 ? em1[i] : em0[i]);
            s1[i] += m; s2[i] += m * m;
            mn[i] = fminf(mn[i], m); mx[i] = fmaxf(mx[i], m);
        }
#pragma unroll
        for (int i = 0; i < 8; ++i) {
            float m = xid[i] + (float)x1[i] + (sg1 ? em1[i] : em0[i]);
            s1[i] += m; s2[i] += m * m;
            mn[i] = fminf(mn[i], m); mx[i] = fmaxf(mx[i], m);
        }
    }
    if (jj < degc) {
        const int e0 = se[jj];
        bf16x8 x0 = *(const bf16x8*)(XG + (size_t)(e0 >> 1) * XGW + 2048 + g);
        const int sg0 = e0 & 1;
#pragma unroll
        for (int i = 0; i < 8; ++i) {
            float m = xid[i] + (float)x0[i] + (sg0 ? em1[i] : em0[i]);
            s1[i] += m; s2[i] += m * m;
            mn[i] = fminf(mn[i], m); mx[i] = fmaxf(mx[i], m);
        }
    }
    for (int j = 64; j < deg; ++j) {
        const int e0 = epack[j0 + j];
        bf16x8 x0 = *(const bf16x8*)(XG + (size_t)(e0 >> 1) * XGW + 2048 + g);
        const int sg0 = e0 & 1;
#pragma unroll
        for (int i = 0; i < 8; ++i) {
            float m = xid[i] + (float)x0[i] + (sg0 ? em1[i] : em0[i]);
            s1[i] += m; s2[i] += m * m;
            mn[i] = fminf(mn[i], m); mx[i] = fmaxf(mx[i], m);
        }
    }
    const int c = deg;
    const float degf = fmaxf((float)c, 1.0f);
    const float rdeg = 1.0f / degf;
    bf16x8 vmean, vmn, vmx, vsd;
#pragma unroll
    for (int i = 0; i < 8; ++i) {
        float mean = s1[i] * rdeg;
        float var = s2[i] * rdeg - mean * mean;
        float sd = sqrtf(fmaxf(var, 0.f) + EPS_STD_);
        float mnv = (c == 0) ? 0.f : mn[i];
        float mxv = (c == 0) ? 0.f : mx[i];
        vmean[i] = (__bf16)mean; vmn[i] = (__bf16)mnv; vmx[i] = (__bf16)mxv; vsd[i] = (__bf16)sd;
    }
    const int t = g >> 9, d = g & 511;
    __bf16* base = AB + (size_t)n * 8192 + (size_t)t * 2048 + d;
    *(bf16x8*)(base + 0 * DD) = vmean;
    *(bf16x8*)(base + 1 * DD) = vmn;
    *(bf16x8*)(base + 2 * DD) = vmx;
    *(bf16x8*)(base + 3 * DD) = vsd;
}

// ---------------- batchnorm apply (+ pooled-sum on last layer) ----------------
__global__ void k_bnapply(const float* __restrict__ H, const float* __restrict__ BN,
                          const float* __restrict__ gamma, const float* __restrict__ beta,
                          __bf16* __restrict__ XB, float* __restrict__ PL,
                          const int* __restrict__ batch, int last) {
    int idx = blockIdx.x * 256 + threadIdx.x;
    int n = idx >> 9, d = idx & 511;
    float mu = BN[d] * (1.0f / NN);
    float var = BN[512 + d] * (1.0f / NN) - mu * mu;
    float v = gamma[d] * (H[idx] - mu) * rsqrtf(var + EPS_BN_) + beta[d];
    v = fmaxf(v, 0.f);
    if (last) atomicAdd(&PL[(size_t)batch[n] * DD + d], v);
    else XB[idx] = (__bf16)v;
}

// ---------------- readout: fc1 + prelu (256 blocks), then fc_out + log_softmax ----------------
__global__ __launch_bounds__(128) void k_fc1(const float* __restrict__ PL, const float* __restrict__ W1,
                                             const float* __restrict__ b1, const float* __restrict__ pa,
                                             float* __restrict__ Z) {
    const int g = blockIdx.x >> 3;
    const int j = (blockIdx.x & 7) * 128 + threadIdx.x;
    __shared__ float pl[512];
    for (int i = threadIdx.x; i < 512; i += 128) pl[i] = PL[(size_t)g * 512 + i];
    __syncthreads();
    const float* w = W1 + j;
    float s0 = 0.f, s1 = 0.f, s2 = 0.f, s3 = 0.f;
#pragma unroll 2
    for (int f = 0; f < 512; f += 4) {
        s0 += pl[f + 0] * w[(size_t)(f + 0) * 1024];
        s1 += pl[f + 1] * w[(size_t)(f + 1) * 1024];
        s2 += pl[f + 2] * w[(size_t)(f + 2) * 1024];
        s3 += pl[f + 3] * w[(size_t)(f + 3) * 1024];
    }
    float s = b1[j] + ((s0 + s1) + (s2 + s3));
    const float a = *pa;
    Z[(size_t)g * 1024 + j] = s > 0.f ? s : a * s;
}

__global__ __launch_bounds__(64) void k_out(const float* __restrict__ Z, const float* __restrict__ Wo,
                                            const float* __restrict__ bo, float* __restrict__ out) {
    const int g = blockIdx.x, t = threadIdx.x;
    float part[NC];
#pragma unroll
    for (int c = 0; c < NC; ++c) part[c] = 0.f;
    for (int f = t; f < 1024; f += 64) {
        const float zv = Z[(size_t)g * 1024 + f];
#pragma unroll
        for (int c = 0; c < NC; ++c) part[c] += zv * Wo[(size_t)f * NC + c];
    }
#pragma unroll
    for (int off = 32; off > 0; off >>= 1)
#pragma unroll
        for (int c = 0; c < NC; ++c) part[c] += __shfl_down(part[c], off);
    if (t == 0) {
        float lg[NC], mxv = -FLT_MAX;
#pragma unroll
        for (int c = 0; c < NC; ++c) { lg[c] = part[c] + bo[c]; mxv = fmaxf(mxv, lg[c]); }
        float se = 0.f;
#pragma unroll
        for (int c = 0; c < NC; ++c) se += expf(lg[c] - mxv);
        const float lse = mxv + logf(se);
#pragma unroll
        for (int c = 0; c < NC; ++c) out[g * NC + c] = lg[c] - lse;
    }
}

extern "C" void kernel_launch(void* const* d_in, const int* in_sizes, int n_in,
                              void* d_out, int out_size, void* d_ws, size_t ws_size,
                              hipStream_t stream) {
    const float* node_emb_w = (const float*)d_in[0];
    const float* edge_emb_w = (const float*)d_in[1];
    const float* pe_w   = (const float*)d_in[2];
    const float* pe_b   = (const float*)d_in[3];
    const float* edge_enc_w = (const float*)d_in[4];
    const float* edge_enc_b = (const float*)d_in[5];
    const float* pre_w  = (const float*)d_in[6];
    const float* pre_b  = (const float*)d_in[7];
    const float* post_w = (const float*)d_in[8];
    const float* post_b = (const float*)d_in[9];
    const float* lin_w  = (const float*)d_in[10];
    const float* lin_b  = (const float*)d_in[11];
    const float* bn_gamma = (const float*)d_in[12];
    const float* bn_beta  = (const float*)d_in[13];
    const float* acts   = (const float*)d_in[14];
    const float* fc1_w  = (const float*)d_in[15];
    const float* fc1_b  = (const float*)d_in[16];
    const float* fc_out_w = (const float*)d_in[17];
    const float* fc_out_b = (const float*)d_in[18];
    const float* prelu_a  = (const float*)d_in[19];
    const int* global_idx = (const int*)d_in[20];
    const int* sgn        = (const int*)d_in[21];
    const int* edge_index = (const int*)d_in[22];
    const int* batch      = (const int*)d_in[23];
    float* out = (float*)d_out;

    char* W = (char*)d_ws;
    size_t off = 0;
    auto alloc = [&](size_t bytes) { void* p = W + off; off += (bytes + 63) & ~(size_t)63; return p; };
    __bf16* XB    = (__bf16*)alloc((size_t)NN * DD * 2);
    float*  H     = (float*)alloc((size_t)NN * DD * 4);
    __bf16* XG    = (__bf16*)alloc((size_t)NN * XGW * 2);
    __bf16* AB    = (__bf16*)alloc((size_t)NN * 8192 * 2);
    float*  OF    = (float*)alloc((size_t)NN * DD * 4);
    __bf16* GWPb  = (__bf16*)alloc((size_t)6 * NN * 512 * 2);
    __bf16* OB    = (__bf16*)alloc((size_t)NN * DD * 2);
    __bf16* WCAT  = (__bf16*)alloc((size_t)2 * 4608 * 512 * 2);
    __bf16* WTT   = (__bf16*)alloc((size_t)2 * NT * 384 * 2048 * 2);
    __bf16* WLINT = (__bf16*)alloc((size_t)2 * 512 * 512 * 2);
    float*  EM    = (float*)alloc((size_t)2 * 2 * 2048 * 4);
    float*  BN    = (float*)alloc(1024 * 4);
    float*  PL    = (float*)alloc((size_t)NG * DD * 4);
    float*  ZB    = (float*)alloc((size_t)NG * 1024 * 4);
    float*  AMP   = (float*)alloc(NN * 4);
    float*  RAMP  = (float*)alloc(NN * 4);
    int*    CNT   = (int*)alloc(NN * 4);      // CNT + FILL adjacent for one memset
    int*    FILL  = (int*)alloc(NN * 4);
    int*    OFFS  = (int*)alloc((NN + 1) * 4);
    int*    EPACK = (int*)alloc(NE * 4);

    const int* src = edge_index;
    const int* dst = edge_index + NE;

    hipMemsetAsync(CNT, 0, 2 * NN * sizeof(int), stream);
    k_count<<<(NE + 255) / 256, 256, 0, stream>>>(dst, CNT);
    k_scan_bx<<<2001, 1024, 0, stream>>>(CNT, OFFS, AMP, RAMP,
                                         node_emb_w, acts, pe_w, pe_b, global_idx, XB);
    k_fill<<<(NE + 255) / 256, 256, 0, stream>>>(src, dst, sgn, OFFS, FILL, EPACK);
    // both layers' weight prep in one launch
    k_tr<<<2 * 5696, 256, 0, stream>>>(pre_w, post_w, lin_w,
                                       edge_emb_w, edge_enc_w, edge_enc_b, pre_b,
                                       WCAT, WTT, WLINT, EM);

    for (int l = 0; l < 2; ++l) {
        const float* post_b_l = post_b + (size_t)l * NT * FO;
        const float* lin_b_l  = lin_b  + (size_t)l * DD;
        __bf16* WCATl  = WCAT  + (size_t)l * 4608 * 512;
        __bf16* WTTl   = WTT   + (size_t)l * NT * 384 * 2048;
        __bf16* WLINTl = WLINT + (size_t)l * 512 * 512;
        float*  EMl    = EM    + (size_t)l * 4096;

        k_xg<<<dim3(36, 32), 256, 0, stream>>>(XB, WCATl, post_b_l, XG, OF, BN, PL, l == 1);
        k_agg<<<NN, 256, 0, stream>>>(XG, EMl, OFFS, CNT, EPACK, AB);
        k_gw<<<768, 256, 0, stream>>>(AB, WTTl, AMP, RAMP, GWPb);
        k_combine<<<NN * DD / 2048, 256, 0, stream>>>(OF, GWPb, OB);
        k_lin<<<dim3(4, 63), 256, 0, stream>>>(OB, WLINTl, lin_b_l, H, BN);
        k_bnapply<<<NN * DD / 256, 256, 0, stream>>>(H, BN, bn_gamma + (size_t)l * DD,
                                                     bn_beta + (size_t)l * DD, XB, PL, batch, l == 1);
    }

    k_fc1<<<256, 128, 0, stream>>>(PL, fc1_w, fc1_b, prelu_a, ZB);
    k_out<<<NG, 64, 0, stream>>>(ZB, fc_out_w, fc_out_b, out);
}

// Round 12
// 472.033 us; speedup vs baseline: 1.0106x; 1.0106x over previous
//
#include <hip/hip_runtime.h>
#include <hip/hip_bf16.h>
#include <float.h>

#define NN 4000      // nodes
#define NE 20000     // edges
#define DD 512       // D
#define NT 4         // towers
#define FO 128       // F_OUT
#define NG 32
#define NC 10
#define XGW 4096     // XG row width: 2048 xi + 2048 xj (gx goes to OF)
#define AVGLOG 1.2548916493836102f
#define EPS_STD_ 1e-5f
#define EPS_BN_ 1e-5f

typedef __bf16 bf16x8 __attribute__((ext_vector_type(8)));
typedef float  f32x4  __attribute__((ext_vector_type(4)));

__device__ __forceinline__ void async_copy16(const void* g, void* l) {
    __builtin_amdgcn_global_load_lds((const __attribute__((address_space(1))) void*)g,
                                     (__attribute__((address_space(3))) void*)l, 16, 0, 0);
}

// =============== k_xg: XG[n][0:4096] = XB @ [Wi|Wj]^T (bf16); OF = XB @ W0^T + post_b (fp32) ===============
// 128x128 tile, K=512, BK=32 (proven core). grid (36, 32): x<32 -> XG, x>=32 -> OF.
__global__ __launch_bounds__(256) void k_xg(const __bf16* __restrict__ XB, const __bf16* __restrict__ WCAT,
                                            const float* __restrict__ pb,
                                            __bf16* __restrict__ XG, float* __restrict__ OF,
                                            float* __restrict__ BN, float* __restrict__ PL, int zero_pl) {
    const int m0 = blockIdx.y * 128, n0 = blockIdx.x * 128;
    __shared__ __bf16 As[128 * 32];
    __shared__ __bf16 Bs[128 * 32];
    const int tid = threadIdx.x;
    const int wave = tid >> 6, lane = tid & 63;
    const int wm = (wave >> 1) * 64, wn = (wave & 1) * 64;
    const int fr = lane & 15, fq = lane >> 4;
    const int fk = fq * 8;
    const int srow = lane >> 2, skc = (lane & 3) * 8;

    f32x4 acc[4][4];
    const f32x4 zero = {0.f, 0.f, 0.f, 0.f};
#pragma unroll
    for (int i = 0; i < 4; ++i)
#pragma unroll
        for (int j = 0; j < 4; ++j) acc[i][j] = zero;

    for (int k0 = 0; k0 < 512; k0 += 32) {
#pragma unroll
        for (int q = 0; q < 2; ++q) {
            const int row = wave * 32 + q * 16 + srow;
            int ar = m0 + row; if (ar > NN - 1) ar = NN - 1;
            async_copy16(XB + (size_t)ar * 512 + k0 + skc, As + wave * 1024 + q * 512);
            async_copy16(WCAT + (size_t)(n0 + row) * 512 + k0 + skc, Bs + wave * 1024 + q * 512);
        }
        __syncthreads();
        bf16x8 af[4], bfr[4];
#pragma unroll
        for (int mi = 0; mi < 4; ++mi) af[mi]  = *(const bf16x8*)(As + (wm + mi * 16 + fr) * 32 + fk);
#pragma unroll
        for (int ni = 0; ni < 4; ++ni) bfr[ni] = *(const bf16x8*)(Bs + (wn + ni * 16 + fr) * 32 + fk);
#pragma unroll
        for (int mi = 0; mi < 4; ++mi)
#pragma unroll
            for (int ni = 0; ni < 4; ++ni)
                acc[mi][ni] = __builtin_amdgcn_mfma_f32_16x16x32_bf16(af[mi], bfr[ni], acc[mi][ni], 0, 0, 0);
        __syncthreads();
    }
    if (n0 < 4096) {
#pragma unroll
        for (int mi = 0; mi < 4; ++mi) {
#pragma unroll
            for (int ni = 0; ni < 4; ++ni) {
                const int col = n0 + wn + ni * 16 + fr;
                const int rb = m0 + wm + mi * 16 + fq * 4;
#pragma unroll
                for (int r = 0; r < 4; ++r) {
                    const int rowc = rb + r;
                    if (rowc < NN) XG[(size_t)rowc * XGW + col] = (__bf16)acc[mi][ni][r];
                }
            }
        }
    } else {
        const int ocb = n0 - 4096;
#pragma unroll
        for (int mi = 0; mi < 4; ++mi) {
#pragma unroll
            for (int ni = 0; ni < 4; ++ni) {
                const int oc = ocb + wn + ni * 16 + fr;
                const float bv = pb[oc];
                const int rb = m0 + wm + mi * 16 + fq * 4;
#pragma unroll
                for (int r = 0; r < 4; ++r) {
                    const int rowc = rb + r;
                    if (rowc < NN) OF[(size_t)rowc * 512 + oc] = acc[mi][ni][r] + bv;
                }
            }
        }
    }
    if (blockIdx.x == 32 && blockIdx.y == 0) {
        BN[tid] = 0.f; BN[256 + tid] = 0.f; BN[512 + tid] = 0.f; BN[768 + tid] = 0.f;
        if (zero_pl)
            for (int i = tid; i < NG * DD; i += 256) PL[i] = 0.f;
    }
}

// =============== k_gw: tower GEMM 128x128, split-K=2, BK=32, XCD-swizzled ===============
// 1D grid 768. Decode so the 3 same-A blocks (xg=0..2) share bid%8 -> same XCD (L2 A-sharing).
__global__ __launch_bounds__(256) void k_gw(const __bf16* __restrict__ AB, const __bf16* __restrict__ WTT,
                                            const float* __restrict__ amp, const float* __restrict__ ramp,
                                            __bf16* __restrict__ GWPb) {
    const int bid = blockIdx.x;
    const int xcd = bid & 7;
    const int q = bid >> 3;        // 0..95
    const int xg = q % 3;          // weight group: 0:P1 w=1, 1:P2 w=amp, 2:P3 w=ramp
    const int ghi = q / 3;         // 0..31
    const int g = ghi * 8 + xcd;   // 0..255 = y + 32*z
    const int y = g & 31, z = g >> 5;
    const int t = z & 3, kh = z >> 2;
    const int m0 = y * 128;
    const __bf16* A  = AB  + (size_t)t * 2048 + (size_t)kh * 1024;
    const __bf16* BT = WTT + (size_t)t * 384 * 2048 + (size_t)xg * 128 * 2048 + (size_t)kh * 1024;
    __shared__ __bf16 As[128 * 32];
    __shared__ __bf16 Bs[128 * 32];
    const int tid = threadIdx.x;
    const int wave = tid >> 6, lane = tid & 63;
    const int wm = (wave >> 1) * 64, wn = (wave & 1) * 64;
    const int fr = lane & 15, fq = lane >> 4;
    const int fk = fq * 8;
    const int srow = lane >> 2, skc = (lane & 3) * 8;

    f32x4 acc[4][4];
    const f32x4 zero = {0.f, 0.f, 0.f, 0.f};
#pragma unroll
    for (int i = 0; i < 4; ++i)
#pragma unroll
        for (int j = 0; j < 4; ++j) acc[i][j] = zero;

    for (int k0 = 0; k0 < 1024; k0 += 32) {
#pragma unroll
        for (int p = 0; p < 2; ++p) {
            const int row = wave * 32 + p * 16 + srow;
            int ar = m0 + row; if (ar > NN - 1) ar = NN - 1;
            async_copy16(A + (size_t)ar * 8192 + k0 + skc, As + wave * 1024 + p * 512);
            async_copy16(BT + (size_t)row * 2048 + k0 + skc, Bs + wave * 1024 + p * 512);
        }
        __syncthreads();
        bf16x8 af[4], bfr[4];
#pragma unroll
        for (int mi = 0; mi < 4; ++mi) af[mi]  = *(const bf16x8*)(As + (wm + mi * 16 + fr) * 32 + fk);
#pragma unroll
        for (int ni = 0; ni < 4; ++ni) bfr[ni] = *(const bf16x8*)(Bs + (wn + ni * 16 + fr) * 32 + fk);
#pragma unroll
        for (int mi = 0; mi < 4; ++mi)
#pragma unroll
            for (int ni = 0; ni < 4; ++ni)
                acc[mi][ni] = __builtin_amdgcn_mfma_f32_16x16x32_bf16(af[mi], bfr[ni], acc[mi][ni], 0, 0, 0);
        __syncthreads();
    }
    const int p = xg * 2 + kh;
    __bf16* P = GWPb + (size_t)p * NN * 512 + (size_t)t * 128;
#pragma unroll
    for (int mi = 0; mi < 4; ++mi) {
        const int rb = m0 + wm + mi * 16 + fq * 4;
#pragma unroll
        for (int r = 0; r < 4; ++r) {
            const int row = rb + r;
            if (row < NN) {
                const float w = (xg == 0) ? 1.0f : (xg == 1 ? amp[row] : ramp[row]);
#pragma unroll
                for (int ni = 0; ni < 4; ++ni)
                    P[(size_t)row * 512 + wn + ni * 16 + fr] = (__bf16)(acc[mi][ni][r] * w);
            }
        }
    }
}

// OB[n][c] = OF[n][c] + sum of 6 bf16 partial planes -> bf16. grid 1000 x 256, 8 elems/thread.
__global__ void k_combine(const float* __restrict__ OF, const __bf16* __restrict__ GWPb,
                          __bf16* __restrict__ OB) {
    const size_t idx8 = ((size_t)blockIdx.x * 256 + threadIdx.x) * 8;
    float4 o0 = *(const float4*)(OF + idx8);
    float4 o1 = *(const float4*)(OF + idx8 + 4);
    float s[8] = {o0.x, o0.y, o0.z, o0.w, o1.x, o1.y, o1.z, o1.w};
#pragma unroll
    for (int p = 0; p < 6; ++p) {
        bf16x8 g = *(const bf16x8*)(GWPb + (size_t)p * NN * 512 + idx8);
#pragma unroll
        for (int i = 0; i < 8; ++i) s[i] += (float)g[i];
    }
    bf16x8 ov;
#pragma unroll
    for (int i = 0; i < 8; ++i) ov[i] = (__bf16)s[i];
    *(bf16x8*)(OB + idx8) = ov;
}

// =============== k_lin: H = OB @ lin_w^T + lin_b (64x128 tile) + fused BN stats ===============
__global__ __launch_bounds__(256) void k_lin(const __bf16* __restrict__ OB, const __bf16* __restrict__ WLINT,
                                             const float* __restrict__ bl, float* __restrict__ H,
                                             float* __restrict__ BN) {
    const int n0c = blockIdx.x * 128, m0 = blockIdx.y * 64;
    __shared__ __bf16 As[64 * 32];
    __shared__ __bf16 Bs[128 * 32];
    __shared__ float bnS[128], bnQ[128];
    const int tid = threadIdx.x;
    if (tid < 128) { bnS[tid] = 0.f; bnQ[tid] = 0.f; }
    const int wave = tid >> 6, lane = tid & 63;
    const int wr = wave >> 1, wc = wave & 1;
    const int fr = lane & 15, fq = lane >> 4;
    f32x4 acc[2][4];
    const f32x4 zero = {0.f, 0.f, 0.f, 0.f};
#pragma unroll
    for (int i = 0; i < 2; ++i)
#pragma unroll
        for (int j = 0; j < 4; ++j) acc[i][j] = zero;

    const int ar = tid >> 2, akc = (tid & 3) * 8;
    int arow = m0 + ar; if (arow > NN - 1) arow = NN - 1;
    for (int k0 = 0; k0 < 512; k0 += 32) {
        async_copy16(OB + (size_t)arow * 512 + k0 + akc, As + tid * 8);
#pragma unroll
        for (int i = 0; i < 2; ++i) {
            const int cb = tid + 256 * i;
            const int br = cb >> 2, bkc = (cb & 3) * 8;
            async_copy16(WLINT + (size_t)(n0c + br) * 512 + k0 + bkc, Bs + cb * 8);
        }
        __syncthreads();
        bf16x8 a[2], b[4];
#pragma unroll
        for (int mi = 0; mi < 2; ++mi) a[mi] = *(const bf16x8*)(As + (wr * 32 + mi * 16 + fr) * 32 + fq * 8);
#pragma unroll
        for (int ni = 0; ni < 4; ++ni) b[ni] = *(const bf16x8*)(Bs + (wc * 64 + ni * 16 + fr) * 32 + fq * 8);
#pragma unroll
        for (int mi = 0; mi < 2; ++mi)
#pragma unroll
            for (int ni = 0; ni < 4; ++ni)
                acc[mi][ni] = __builtin_amdgcn_mfma_f32_16x16x32_bf16(a[mi], b[ni], acc[mi][ni], 0, 0, 0);
        __syncthreads();
    }
#pragma unroll
    for (int ni = 0; ni < 4; ++ni) {
        const int lc = wc * 64 + ni * 16 + fr;
        const int col = n0c + lc;
        const float bv = bl[col];
        float s = 0.f, q = 0.f;
#pragma unroll
        for (int mi = 0; mi < 2; ++mi) {
#pragma unroll
            for (int r = 0; r < 4; ++r) {
                const int rowc = m0 + wr * 32 + mi * 16 + fq * 4 + r;
                if (rowc < NN) {
                    const float v = acc[mi][ni][r] + bv;
                    H[(size_t)rowc * 512 + col] = v;
                    s += v; q += v * v;
                }
            }
        }
        atomicAdd(&bnS[lc], s); atomicAdd(&bnQ[lc], q);
    }
    __syncthreads();
    if (tid < 128) {
        atomicAdd(&BN[n0c + tid], bnS[tid]);
        atomicAdd(&BN[512 + n0c + tid], bnQ[tid]);
    }
}

// =============== fused weight transpose (64x64 vectorized tiles) + edge-message table ===============
// 64x64 fp32 -> bf16^T tile. Reads: float4, 256B contiguous per 16 lanes. LDS pad 68 (write-phase
// reads 2-way bank aliased = free). Stores: bf16x8, 4 consecutive lanes = 64B contiguous.
__device__ __forceinline__ void tr64(const float* __restrict__ S, int sld,
                                     __bf16* __restrict__ D, int dld) {
    __shared__ float ts[64][68];
    const int tid = threadIdx.x;
    const int rr = tid >> 4;            // 0..15
    const int cc = (tid & 15) * 4;      // 0,4,..60
#pragma unroll
    for (int i = 0; i < 4; ++i)
        *(f32x4*)&ts[rr + i * 16][cc] = *(const f32x4*)(S + (size_t)(rr + i * 16) * sld + cc);
    __syncthreads();
    const int c = tid >> 2;             // dest row 0..63
    const int r0 = (tid & 3) * 16;      // dest col base
#pragma unroll
    for (int h = 0; h < 2; ++h) {
        bf16x8 v;
#pragma unroll
        for (int i = 0; i < 8; ++i) v[i] = (__bf16)ts[r0 + h * 8 + i][c];
        *(bf16x8*)(D + (size_t)c * dld + r0 + h * 8) = v;
    }
}

// per-layer jobs: [0,512) pre Wi/Wj; [512,576) W0; [576,1344) WTT; [1344,1408) WLINT; [1408,1472) EM
__global__ __launch_bounds__(256) void k_tr(const float* __restrict__ pre_w, const float* __restrict__ post_w,
                                            const float* __restrict__ lin_w,
                                            const float* __restrict__ eemb, const float* __restrict__ eew_b,
                                            const float* __restrict__ eeb_b, const float* __restrict__ pre_b,
                                            __bf16* __restrict__ WCAT, __bf16* __restrict__ WTT,
                                            __bf16* __restrict__ WLINT, float* __restrict__ EM) {
    int id = blockIdx.x;
    const int lay = (id >= 1472) ? 1 : 0;
    id -= lay * 1472;
    const float* pw   = pre_w  + (size_t)lay * NT * 3 * 512 * 512;
    const float* pow_ = post_w + (size_t)lay * NT * 6656 * 128;
    const float* lw   = lin_w  + (size_t)lay * 512 * 512;
    const float* eew  = eew_b  + (size_t)lay * 50 * 512;
    const float* eeb  = eeb_b  + (size_t)lay * 512;
    const float* pb   = pre_b  + (size_t)lay * NT * 512;
    __bf16* WCATl  = WCAT  + (size_t)lay * 4608 * 512;
    __bf16* WTTl   = WTT   + (size_t)lay * NT * 384 * 2048;
    __bf16* WLINTl = WLINT + (size_t)lay * 512 * 512;
    float*  EMl    = EM    + (size_t)lay * 4096;
    if (id < 512) {
        const int z = id >> 6, r = id & 63;
        const int t = z & 3, half = z >> 2;
        const int y = r >> 3, x = r & 7;
        const float* S = pw + ((size_t)(t * 1536 + half * 512 + y * 64)) * 512 + x * 64;
        __bf16* D = WCATl + ((size_t)(half * 2048 + t * 512 + x * 64)) * 512 + y * 64;
        tr64(S, 512, D, 512);
    } else if (id < 576) {
        const int id2 = id - 512;
        const int t = id2 >> 4, r = id2 & 15;
        const int y = r >> 1, x = r & 1;
        const float* S = pow_ + ((size_t)(t * 6656 + y * 64)) * 128 + x * 64;
        __bf16* D = WCATl + ((size_t)(4096 + t * 128 + x * 64)) * 512 + y * 64;
        tr64(S, 128, D, 512);
    } else if (id < 1344) {
        const int id3 = id - 576;
        const int z = id3 >> 6, r = id3 & 63;
        const int t = z / 3, w = z % 3;
        const int y = r >> 1, x = r & 1;
        const float* S = pow_ + ((size_t)(t * 6656 + 512 + w * 2048 + y * 64)) * 128 + x * 64;
        __bf16* D = WTTl + (size_t)t * 384 * 2048 + ((size_t)(w * 128 + x * 64)) * 2048 + y * 64;
        tr64(S, 128, D, 2048);
    } else if (id < 1408) {
        const int id4 = id - 1344;
        const int y = id4 >> 3, x = id4 & 7;
        const float* S = lw + (size_t)y * 64 * 512 + x * 64;
        __bf16* D = WLINTl + (size_t)x * 64 * 512 + y * 64;
        tr64(S, 512, D, 512);
    } else {
        __shared__ float eks[512];
        __shared__ float part[4][64];
        const int tid = threadIdx.x;
        const int id5 = id - 1408;
        const int k = id5 >> 5;
        const int g0 = (id5 & 31) * 64;
#pragma unroll
        for (int h = 0; h < 2; ++h) {
            const int f = tid + h * 256;
            float s = eeb[f];
            for (int c = 0; c < 50; ++c) s += eemb[k * 50 + c] * eew[(size_t)c * 512 + f];
            eks[f] = s;
        }
        __syncthreads();
        const int wave = tid >> 6, lane = tid & 63;
        const int g = g0 + lane;
        const int t = g >> 9, d = g & 511;
        const float* Wp = pw + ((size_t)(t * 1536 + 1024)) * 512 + d;
        float s = 0.f;
        const int f0 = wave * 128;
#pragma unroll 4
        for (int f = f0; f < f0 + 128; ++f) s += eks[f] * Wp[(size_t)f * 512];
        part[wave][lane] = s;
        __syncthreads();
        if (tid < 64) {
            const int gg = g0 + tid;
            EMl[k * 2048 + gg] = pb[gg] + part[0][tid] + part[1][tid] + part[2][tid] + part[3][tid];
        }
    }
}

// ---------------- graph prep ----------------
__global__ void k_count(const int* __restrict__ dst, int* __restrict__ cnt) {
    int e = blockIdx.x * 256 + threadIdx.x;
    if (e < NE) atomicAdd(&cnt[dst[e]], 1);
}

__global__ __launch_bounds__(1024) void k_scan_bx(const int* __restrict__ cnt, int* __restrict__ offs,
                                                  float* __restrict__ amp, float* __restrict__ ramp,
                                                  const float* __restrict__ nemb, const float* __restrict__ acts,
                                                  const float* __restrict__ pew, const float* __restrict__ peb,
                                                  const int* __restrict__ gidx, __bf16* __restrict__ XB) {
    const int t = threadIdx.x;
    if (blockIdx.x == 0) {
        __shared__ int part[1024];
        const int base = t * 4;
        int loc[4]; int s = 0;
#pragma unroll
        for (int i = 0; i < 4; ++i) { int v = (base + i < NN) ? cnt[base + i] : 0; loc[i] = s; s += v; }
        part[t] = s;
        __syncthreads();
        for (int o = 1; o < 1024; o <<= 1) {
            int v = (t >= o) ? part[t - o] : 0;
            __syncthreads();
            part[t] += v;
            __syncthreads();
        }
        const int pre = (t > 0) ? part[t - 1] : 0;
#pragma unroll
        for (int i = 0; i < 4; ++i) if (base + i < NN) offs[base + i] = pre + loc[i];
        if (t == 1023) offs[NN] = part[1023];
        for (int n = t; n < NN; n += 1024) {
            float deg = fmaxf((float)cnt[n], 1.0f);
            float a = logf(deg + 1.0f) / AVGLOG;
            amp[n] = a; ramp[n] = 1.0f / a;
        }
    } else {
        const int idx = (blockIdx.x - 1) * 1024 + t;
        const int n = idx >> 9, d = idx & 511;
        float v = nemb[(size_t)gidx[n] * DD + d] + acts[n * 2] * pew[d] + acts[n * 2 + 1] * pew[DD + d] + peb[d];
        XB[idx] = (__bf16)v;
    }
}

// epack = (src << 1) | sign
__global__ void k_fill(const int* __restrict__ src, const int* __restrict__ dst,
                       const int* __restrict__ sgn, const int* __restrict__ offs,
                       int* __restrict__ fill, int* __restrict__ epack) {
    int e = blockIdx.x * 256 + threadIdx.x;
    if (e < NE) {
        int d = dst[e];
        int pos = offs[d] + atomicAdd(&fill[d], 1);
        epack[pos] = (src[e] << 1) | sgn[e];
    }
}

// ---------------- aggregation: one block per dst node, LDS index stage + 2-way unrolled ----------------
__global__ __launch_bounds__(256) void k_agg(const __bf16* __restrict__ XG, const float* __restrict__ EM,
                                             const int* __restrict__ offs, const int* __restrict__ cnt,
                                             const int* __restrict__ epack, __bf16* __restrict__ AB) {
    const int n = blockIdx.x;
    const int g = threadIdx.x * 8;
    __shared__ int se[64];
    const int j0 = offs[n];
    const int deg = offs[n + 1] - j0;
    const int degc = deg < 64 ? deg : 64;
    if (threadIdx.x < degc) se[threadIdx.x] = epack[j0 + threadIdx.x];
    __syncthreads();
    float xid[8], em0[8], em1[8];
    {
        bf16x8 xb = *(const bf16x8*)(XG + (size_t)n * XGW + g);
#pragma unroll
        for (int i = 0; i < 8; ++i) xid[i] = (float)xb[i];
    }
    *(float4*)&em0[0] = *(const float4*)&EM[g];
    *(float4*)&em0[4] = *(const float4*)&EM[g + 4];
    *(float4*)&em1[0] = *(const float4*)&EM[2048 + g];
    *(float4*)&em1[4] = *(const float4*)&EM[2048 + g + 4];
    float s1[8], s2[8], mn[8], mx[8];
#pragma unroll
    for (int i = 0; i < 8; ++i) { s1[i] = 0.f; s2[i] = 0.f; mn[i] = FLT_MAX; mx[i] = -FLT_MAX; }

    int jj = 0;
    for (; jj + 2 <= degc; jj += 2) {
        const int e0 = se[jj], e1 = se[jj + 1];
        bf16x8 x0 = *(const bf16x8*)(XG + (size_t)(e0 >> 1) * XGW + 2048 + g);
        bf16x8 x1 = *(const bf16x8*)(XG + (size_t)(e1 >> 1) * XGW + 2048 + g);
        const int sg0 = e0 & 1, sg1 = e1 & 1;
#pragma unroll
        for (int i = 0; i < 8; ++i) {
            float m = xid[i] + (float)x0[i] + (sg0 ? em1[i] : em0[i]);
            s1[i] += m; s2[i] += m * m;
            mn[i] = fminf(mn[i], m); mx[i] = fmaxf(mx[i], m);
        }
#pragma unroll
        for (int i = 0; i < 8; ++i) {
            float m = xid[i] + (float)x1[i] + (sg1 ? em1[i] : em0[i]);
            s1[i] += m; s2[i] += m * m;
            mn[i] = fminf(mn[i], m); mx[i] = fmaxf(mx[i], m);
        }
    }
    if (jj < degc) {
        const int e0 = se[jj];
        bf16x8 x0 = *(const bf16x8*)(XG + (size_t)(e0 >> 1) * XGW + 2048 + g);
        const int sg0 = e0 & 1;
#pragma unroll
        for (int i = 0; i < 8; ++i) {
            float m = xid[i] + (float)x0[i] + (sg0 ? em1[i] : em0[i]);
            s1[i] += m; s2[i] += m * m;
            mn[i] = fminf(mn[i], m); mx[i] = fmaxf(mx[i], m);
        }
    }
    for (int j = 64; j < deg; ++j) {
        const int e0 = epack[j0 + j];
        bf16x8 x0 = *(const bf16x8*)(XG + (size_t)(e0 >> 1) * XGW + 2048 + g);
        const int sg0 = e0 & 1;
#pragma unroll
        for (int i = 0; i < 8; ++i) {
            float m = xid[i] + (float)x0[i] + (sg0 ? em1[i] : em0[i]);
            s1[i] += m; s2[i] += m * m;
            mn[i] = fminf(mn[i], m); mx[i] = fmaxf(mx[i], m);
        }
    }
    const int c = deg;
    const float degf = fmaxf((float)c, 1.0f);
    const float rdeg = 1.0f / degf;
    bf16x8 vmean, vmn, vmx, vsd;
#pragma unroll
    for (int i = 0; i < 8; ++i) {
        float mean = s1[i] * rdeg;
        float var = s2[i] * rdeg - mean * mean;
        float sd = sqrtf(fmaxf(var, 0.f) + EPS_STD_);
        float mnv = (c == 0) ? 0.f : mn[i];
        float mxv = (c == 0) ? 0.f : mx[i];
        vmean[i] = (__bf16)mean; vmn[i] = (__bf16)mnv; vmx[i] = (__bf16)mxv; vsd[i] = (__bf16)sd;
    }
    const int t = g >> 9, d = g & 511;
    __bf16* base = AB + (size_t)n * 8192 + (size_t)t * 2048 + d;
    *(bf16x8*)(base + 0 * DD) = vmean;
    *(bf16x8*)(base + 1 * DD) = vmn;
    *(bf16x8*)(base + 2 * DD) = vmx;
    *(bf16x8*)(base + 3 * DD) = vsd;
}

// ---------------- batchnorm apply (+ pooled-sum on last layer) ----------------
__global__ void k_bnapply(const float* __restrict__ H, const float* __restrict__ BN,
                          const float* __restrict__ gamma, const float* __restrict__ beta,
                          __bf16* __restrict__ XB, float* __restrict__ PL,
                          const int* __restrict__ batch, int last) {
    int idx = blockIdx.x * 256 + threadIdx.x;
    int n = idx >> 9, d = idx & 511;
    float mu = BN[d] * (1.0f / NN);
    float var = BN[512 + d] * (1.0f / NN) - mu * mu;
    float v = gamma[d] * (H[idx] - mu) * rsqrtf(var + EPS_BN_) + beta[d];
    v = fmaxf(v, 0.f);
    if (last) atomicAdd(&PL[(size_t)batch[n] * DD + d], v);
    else XB[idx] = (__bf16)v;
}

// ---------------- readout: fc1 + prelu (256 blocks), then fc_out + log_softmax ----------------
__global__ __launch_bounds__(128) void k_fc1(const float* __restrict__ PL, const float* __restrict__ W1,
                                             const float* __restrict__ b1, const float* __restrict__ pa,
                                             float* __restrict__ Z) {
    const int g = blockIdx.x >> 3;
    const int j = (blockIdx.x & 7) * 128 + threadIdx.x;
    __shared__ float pl[512];
    for (int i = threadIdx.x; i < 512; i += 128) pl[i] = PL[(size_t)g * 512 + i];
    __syncthreads();
    const float* w = W1 + j;
    float s0 = 0.f, s1 = 0.f, s2 = 0.f, s3 = 0.f;
#pragma unroll 2
    for (int f = 0; f < 512; f += 4) {
        s0 += pl[f + 0] * w[(size_t)(f + 0) * 1024];
        s1 += pl[f + 1] * w[(size_t)(f + 1) * 1024];
        s2 += pl[f + 2] * w[(size_t)(f + 2) * 1024];
        s3 += pl[f + 3] * w[(size_t)(f + 3) * 1024];
    }
    float s = b1[j] + ((s0 + s1) + (s2 + s3));
    const float a = *pa;
    Z[(size_t)g * 1024 + j] = s > 0.f ? s : a * s;
}

__global__ __launch_bounds__(64) void k_out(const float* __restrict__ Z, const float* __restrict__ Wo,
                                            const float* __restrict__ bo, float* __restrict__ out) {
    const int g = blockIdx.x, t = threadIdx.x;
    float part[NC];
#pragma unroll
    for (int c = 0; c < NC; ++c) part[c] = 0.f;
    for (int f = t; f < 1024; f += 64) {
        const float zv = Z[(size_t)g * 1024 + f];
#pragma unroll
        for (int c = 0; c < NC; ++c) part[c] += zv * Wo[(size_t)f * NC + c];
    }
#pragma unroll
    for (int off = 32; off > 0; off >>= 1)
#pragma unroll
        for (int c = 0; c < NC; ++c) part[c] += __shfl_down(part[c], off);
    if (t == 0) {
        float lg[NC], mxv = -FLT_MAX;
#pragma unroll
        for (int c = 0; c < NC; ++c) { lg[c] = part[c] + bo[c]; mxv = fmaxf(mxv, lg[c]); }
        float se = 0.f;
#pragma unroll
        for (int c = 0; c < NC; ++c) se += expf(lg[c] - mxv);
        const float lse = mxv + logf(se);
#pragma unroll
        for (int c = 0; c < NC; ++c) out[g * NC + c] = lg[c] - lse;
    }
}

extern "C" void kernel_launch(void* const* d_in, const int* in_sizes, int n_in,
                              void* d_out, int out_size, void* d_ws, size_t ws_size,
                              hipStream_t stream) {
    const float* node_emb_w = (const float*)d_in[0];
    const float* edge_emb_w = (const float*)d_in[1];
    const float* pe_w   = (const float*)d_in[2];
    const float* pe_b   = (const float*)d_in[3];
    const float* edge_enc_w = (const float*)d_in[4];
    const float* edge_enc_b = (const float*)d_in[5];
    const float* pre_w  = (const float*)d_in[6];
    const float* pre_b  = (const float*)d_in[7];
    const float* post_w = (const float*)d_in[8];
    const float* post_b = (const float*)d_in[9];
    const float* lin_w  = (const float*)d_in[10];
    const float* lin_b  = (const float*)d_in[11];
    const float* bn_gamma = (const float*)d_in[12];
    const float* bn_beta  = (const float*)d_in[13];
    const float* acts   = (const float*)d_in[14];
    const float* fc1_w  = (const float*)d_in[15];
    const float* fc1_b  = (const float*)d_in[16];
    const float* fc_out_w = (const float*)d_in[17];
    const float* fc_out_b = (const float*)d_in[18];
    const float* prelu_a  = (const float*)d_in[19];
    const int* global_idx = (const int*)d_in[20];
    const int* sgn        = (const int*)d_in[21];
    const int* edge_index = (const int*)d_in[22];
    const int* batch      = (const int*)d_in[23];
    float* out = (float*)d_out;

    char* W = (char*)d_ws;
    size_t off = 0;
    auto alloc = [&](size_t bytes) { void* p = W + off; off += (bytes + 63) & ~(size_t)63; return p; };
    __bf16* XB    = (__bf16*)alloc((size_t)NN * DD * 2);
    float*  H     = (float*)alloc((size_t)NN * DD * 4);
    __bf16* XG    = (__bf16*)alloc((size_t)NN * XGW * 2);
    __bf16* AB    = (__bf16*)alloc((size_t)NN * 8192 * 2);
    float*  OF    = (float*)alloc((size_t)NN * DD * 4);
    __bf16* GWPb  = (__bf16*)alloc((size_t)6 * NN * 512 * 2);
    __bf16* OB    = (__bf16*)alloc((size_t)NN * DD * 2);
    __bf16* WCAT  = (__bf16*)alloc((size_t)2 * 4608 * 512 * 2);
    __bf16* WTT   = (__bf16*)alloc((size_t)2 * NT * 384 * 2048 * 2);
    __bf16* WLINT = (__bf16*)alloc((size_t)2 * 512 * 512 * 2);
    float*  EM    = (float*)alloc((size_t)2 * 2 * 2048 * 4);
    float*  BN    = (float*)alloc(1024 * 4);
    float*  PL    = (float*)alloc((size_t)NG * DD * 4);
    float*  ZB    = (float*)alloc((size_t)NG * 1024 * 4);
    float*  AMP   = (float*)alloc(NN * 4);
    float*  RAMP  = (float*)alloc(NN * 4);
    int*    CNT   = (int*)alloc(NN * 4);      // CNT + FILL adjacent for one memset
    int*    FILL  = (int*)alloc(NN * 4);
    int*    OFFS  = (int*)alloc((NN + 1) * 4);
    int*    EPACK = (int*)alloc(NE * 4);

    const int* src = edge_index;
    const int* dst = edge_index + NE;

    hipMemsetAsync(CNT, 0, 2 * NN * sizeof(int), stream);
    k_count<<<(NE + 255) / 256, 256, 0, stream>>>(dst, CNT);
    k_scan_bx<<<2001, 1024, 0, stream>>>(CNT, OFFS, AMP, RAMP,
                                         node_emb_w, acts, pe_w, pe_b, global_idx, XB);
    k_fill<<<(NE + 255) / 256, 256, 0, stream>>>(src, dst, sgn, OFFS, FILL, EPACK);
    // both layers' weight prep in one launch (64x64 vectorized tiles)
    k_tr<<<2 * 1472, 256, 0, stream>>>(pre_w, post_w, lin_w,
                                       edge_emb_w, edge_enc_w, edge_enc_b, pre_b,
                                       WCAT, WTT, WLINT, EM);

    for (int l = 0; l < 2; ++l) {
        const float* post_b_l = post_b + (size_t)l * NT * FO;
        const float* lin_b_l  = lin_b  + (size_t)l * DD;
        __bf16* WCATl  = WCAT  + (size_t)l * 4608 * 512;
        __bf16* WTTl   = WTT   + (size_t)l * NT * 384 * 2048;
        __bf16* WLINTl = WLINT + (size_t)l * 512 * 512;
        float*  EMl    = EM    + (size_t)l * 4096;

        k_xg<<<dim3(36, 32), 256, 0, stream>>>(XB, WCATl, post_b_l, XG, OF, BN, PL, l == 1);
        k_agg<<<NN, 256, 0, stream>>>(XG, EMl, OFFS, CNT, EPACK, AB);
        k_gw<<<768, 256, 0, stream>>>(AB, WTTl, AMP, RAMP, GWPb);
        k_combine<<<NN * DD / 2048, 256, 0, stream>>>(OF, GWPb, OB);
        k_lin<<<dim3(4, 63), 256, 0, stream>>>(OB, WLINTl, lin_b_l, H, BN);
        k_bnapply<<<NN * DD / 256, 256, 0, stream>>>(H, BN, bn_gamma + (size_t)l * DD,
                                                     bn_beta + (size_t)l * DD, XB, PL, batch, l == 1);
    }

    k_fc1<<<256, 128, 0, stream>>>(PL, fc1_w, fc1_b, prelu_a, ZB);
    k_out<<<NG, 64, 0, stream>>>(ZB, fc_out_w, fc_out_b, out);
}